// Round 10
// baseline (210.951 us; speedup 1.0000x reference)
//
#include <hip/hip_runtime.h>
#include <hip/hip_cooperative_groups.h>

namespace cg = cooperative_groups;

#define NB 8
#define NC 256
#define FH 64
#define FW 64
#define NS (FH * FW)          // 4096 spatial positions per batch
#define NSAMP 131072
#define MARGIN_F 12.0f
#define NTILES 4096           // 64 x-tiles * 4 y-tiles * 16 (tensor,batch)

typedef float vfloat2 __attribute__((ext_vector_type(2)));

// ---------------------------------------------------------------------------
// fp8 e4m3 (OCP) pack/unpack via gfx950 HW converts.
// ---------------------------------------------------------------------------
__device__ __forceinline__ unsigned pack4_fp8(float f0, float f1, float f2, float f3)
{
    int r = __builtin_amdgcn_cvt_pk_fp8_f32(f0, f1, 0, false);  // bytes 0,1
    r     = __builtin_amdgcn_cvt_pk_fp8_f32(f2, f3, r, true);   // bytes 2,3
    return (unsigned)r;
}

__device__ __forceinline__ void acc_u32(unsigned a, unsigned p, unsigned n, float& d)
{
    const vfloat2 a0 = __builtin_amdgcn_cvt_pk_f32_fp8(a, false);
    const vfloat2 a1 = __builtin_amdgcn_cvt_pk_f32_fp8(a, true);
    const vfloat2 p0 = __builtin_amdgcn_cvt_pk_f32_fp8(p, false);
    const vfloat2 p1 = __builtin_amdgcn_cvt_pk_f32_fp8(p, true);
    const vfloat2 n0 = __builtin_amdgcn_cvt_pk_f32_fp8(n, false);
    const vfloat2 n1 = __builtin_amdgcn_cvt_pk_f32_fp8(n, true);
    float t;
    t = a0.x - p0.x; d += t * t;  t = a0.x - n0.x; d -= t * t;
    t = a0.y - p0.y; d += t * t;  t = a0.y - n0.y; d -= t * t;
    t = a1.x - p1.x; d += t * t;  t = a1.x - n1.x; d -= t * t;
    t = a1.y - p1.y; d += t * t;  t = a1.y - n1.y; d -= t * t;
}

__device__ __forceinline__ void acc_quad(uint4 a, uint4 p, uint4 n, float& d)
{
    acc_u32(a.x, p.x, n.x, d);
    acc_u32(a.y, p.y, n.y, d);
    acc_u32(a.z, p.z, n.z, d);
    acc_u32(a.w, p.w, n.w, d);
}

// ---------------------------------------------------------------------------
// ONE cooperative kernel:
//  phase 1: transpose (B,C,S) fp32 -> (B,S,C) fp8 (R5's verified tile body,
//           grid-stride over 4096 tiles)
//  grid.sync()
//  phase 2: gather + triplet loss (R5's verified one-sample-per-octet body,
//           grid-stride), block partial -> ONE packed u64 atomic:
//           bits 52+: arrival count, bits 0..51: fixed-point (2^20) sum.
//           Block observing count==gridDim.x writes out[0]. No fences.
// ---------------------------------------------------------------------------
__global__ __launch_bounds__(256) void triplet_fused(
    const float* __restrict__ in0, const float* __restrict__ in1,
    unsigned char* __restrict__ tq8, unsigned char* __restrict__ tk8,
    const int*  __restrict__ batch_idx,
    const int2* __restrict__ anchor_yx,
    const int2* __restrict__ pos_yx,
    const int2* __restrict__ neg_yx,
    unsigned long long* __restrict__ ctrl,
    float* __restrict__ out)
{
    __shared__ float tile[64][65];
    const int t = threadIdx.x;

    // zero the packed accumulator (ws is poisoned 0xAA); visible after sync
    if (blockIdx.x == 0 && t == 0) atomicExch(ctrl, 0ull);

    // ---- phase 1: transpose to fp8 ----
    for (int tl = blockIdx.x; tl < NTILES; tl += gridDim.x) {
        __syncthreads();                       // protect LDS tile reuse
        const int xt    = tl & 63;
        const int yt    = (tl >> 6) & 3;
        const int zt    = tl >> 8;             // 0..15
        const int which = zt >> 3;
        const int b     = zt & 7;
        const float* __restrict__ in  = which ? in1 : in0;
        unsigned char* __restrict__ o = which ? tk8 : tq8;

        const int s0 = xt * 64;
        const int c0 = yt * 64;
        const float* __restrict__ inb  = in + (size_t)b * NC * NS;
        unsigned char* __restrict__ outb = o + (size_t)b * NS * NC;

        const int g   = t >> 4;          // 0..15
        const int sl4 = (t & 15) << 2;   // 0,4,...,60
#pragma unroll
        for (int pass = 0; pass < 4; ++pass) {
            const int cl = pass * 16 + g;
            const float4 v = *(const float4*)&inb[(size_t)(c0 + cl) * NS + (s0 + sl4)];
            tile[sl4 + 0][cl] = v.x;
            tile[sl4 + 1][cl] = v.y;
            tile[sl4 + 2][cl] = v.z;
            tile[sl4 + 3][cl] = v.w;
        }
        __syncthreads();

        const int cl4 = (t & 15) << 2;
#pragma unroll
        for (int pass = 0; pass < 4; ++pass) {
            const int sl = pass * 16 + (t >> 4);
            const unsigned w = pack4_fp8(tile[sl][cl4 + 0], tile[sl][cl4 + 1],
                                         tile[sl][cl4 + 2], tile[sl][cl4 + 3]);
            *(unsigned*)&outb[(size_t)(s0 + sl) * NC + (c0 + cl4)] = w;
        }
    }

    cg::this_grid().sync();

    // ---- phase 2: gather (R5 body) ----
    const uint4* __restrict__ tq = (const uint4*)tq8;   // 16 uint4 per vector
    const uint4* __restrict__ tk = (const uint4*)tk8;
    const int ol  = t & 7;          // lane within octet
    const int oct = t >> 3;         // octet id in block, 0..31

    float acc = 0.0f;
    for (int s = blockIdx.x * 32 + oct; s < NSAMP; s += gridDim.x * 32) {
        const int  b  = batch_idx[s];
        const int2 ay = anchor_yx[s];
        const int2 py = pos_yx[s];
        const int2 ny = neg_yx[s];

        const size_t ab = ((size_t)(b * NS) + ay.x * FW + ay.y) * 16;  // uint4 units
        const size_t pb = ((size_t)(b * NS) + py.x * FW + py.y) * 16;
        const size_t nb = ((size_t)(b * NS) + ny.x * FW + ny.y) * 16;

        const uint4 A0 = tq[ab + ol];
        const uint4 A1 = tq[ab + 8 + ol];
        const uint4 P0 = tk[pb + ol];
        const uint4 P1 = tk[pb + 8 + ol];
        const uint4 N0 = tk[nb + ol];
        const uint4 N1 = tk[nb + 8 + ol];

        float d = 0.0f;
        acc_quad(A0, P0, N0, d);
        acc_quad(A1, P1, N1, d);
#pragma unroll
        for (int m = 1; m < 8; m <<= 1) d += __shfl_xor(d, m, 64);
        if (ol == 0) acc += fmaxf(d + MARGIN_F, 0.0f);
    }

    // block reduce (values live only on ol==0 lanes)
#pragma unroll
    for (int m = 1; m < 64; m <<= 1) acc += __shfl_xor(acc, m, 64);
    __shared__ float wsum[4];
    if ((t & 63) == 0) wsum[t >> 6] = acc;
    __syncthreads();

    if (t == 0) {
        const float part = wsum[0] + wsum[1] + wsum[2] + wsum[3];  // >= 0 (relu)
        const unsigned long long fx =
            (unsigned long long)(part * 1048576.0f + 0.5f);        // 2^20 fixed-point
        const unsigned long long packed = (1ull << 52) | fx;
        const unsigned long long newv = atomicAdd(ctrl, packed) + packed;
        if ((unsigned)(newv >> 52) == gridDim.x) {                 // I'm the last block
            const double sum = (double)(newv & ((1ull << 52) - 1)) * (1.0 / 1048576.0);
            out[0] = (float)(sum / (1e-6 + (double)NSAMP));
        }
    }
}

// ---------------------------------------------------------------------------
// Fallback (ws too small): direct strided gather in original layout.
// ---------------------------------------------------------------------------
__global__ __launch_bounds__(256) void triplet_direct(
    const float* __restrict__ q, const float* __restrict__ k,
    const int*  __restrict__ batch_idx,
    const int2* __restrict__ anchor_yx,
    const int2* __restrict__ pos_yx,
    const int2* __restrict__ neg_yx,
    float* __restrict__ out)
{
    const int lane   = threadIdx.x & 63;
    const int wid    = threadIdx.x >> 6;
    const int gwave  = blockIdx.x * 4 + wid;
    const int nwaves = gridDim.x * 4;

    float wsum = 0.0f;
    for (int i = gwave; i < NSAMP; i += nwaves) {
        const int  b  = batch_idx[i];
        const int2 ay = anchor_yx[i];
        const int2 py = pos_yx[i];
        const int2 ny = neg_yx[i];

        const size_t base = (size_t)b * NC * NS;
        const int sa = ay.x * FW + ay.y;
        const int sp = py.x * FW + py.y;
        const int sn = ny.x * FW + ny.y;

        float d = 0.0f;
#pragma unroll
        for (int kk = 0; kk < 4; ++kk) {
            const int c = lane + 64 * kk;
            const float av = q[base + (size_t)c * NS + sa];
            const float pv = k[base + (size_t)c * NS + sp];
            const float nv = k[base + (size_t)c * NS + sn];
            float t;
            t = av - pv; d += t * t;
            t = av - nv; d -= t * t;
        }
#pragma unroll
        for (int m = 1; m < 64; m <<= 1) d += __shfl_xor(d, m, 64);
        if (lane == 0) wsum += fmaxf(d + MARGIN_F, 0.0f);
    }

    __shared__ float bsum[4];
    if (lane == 0) bsum[wid] = wsum;
    __syncthreads();
    if (threadIdx.x == 0) {
        const float invN = 1.0f / (1e-6f + (float)NSAMP);
        atomicAdd(out, (bsum[0] + bsum[1] + bsum[2] + bsum[3]) * invN);
    }
}

extern "C" void kernel_launch(void* const* d_in, const int* in_sizes, int n_in,
                              void* d_out, int out_size, void* d_ws, size_t ws_size,
                              hipStream_t stream)
{
    const float* sketch = (const float*)d_in[0];
    const float* refk   = (const float*)d_in[1];
    const int*   bidx   = (const int*)d_in[2];
    const int2*  ayx    = (const int2*)d_in[3];
    const int2*  pyx    = (const int2*)d_in[4];
    const int2*  nyx    = (const int2*)d_in[5];
    float*       out    = (float*)d_out;

    const size_t tensor_elems = (size_t)NB * NC * NS;        // 8M (8 MB fp8 each)
    const size_t need = 2 * tensor_elems + sizeof(unsigned long long);

    if (ws_size >= need) {
        unsigned char* tq = (unsigned char*)d_ws;
        unsigned char* tk = tq + tensor_elems;
        unsigned long long* ctrl = (unsigned long long*)(tk + tensor_elems);

        // co-resident grid size for cooperative launch (host-side query only;
        // deterministic across calls, graph-capture safe)
        int maxb = 0;
        if (hipOccupancyMaxActiveBlocksPerMultiprocessor(
                &maxb, (const void*)triplet_fused, 256, 0) != hipSuccess || maxb < 1)
            maxb = 4;
        int G = maxb * 256;                 // 256 CUs on MI355X
        if (G > 2048) G = 2048;             // 8 blocks/CU cap (32 waves/CU)

        void* args[] = {
            (void*)&sketch, (void*)&refk, (void*)&tq, (void*)&tk,
            (void*)&bidx, (void*)&ayx, (void*)&pyx, (void*)&nyx,
            (void*)&ctrl, (void*)&out
        };
        (void)hipLaunchCooperativeKernel((const void*)triplet_fused,
                                         dim3(G), dim3(256), args, 0, stream);
    } else {
        (void)hipMemsetAsync(out, 0, sizeof(float), stream);
        triplet_direct<<<4096, 256, 0, stream>>>(
            sketch, refk, bidx, ayx, pyx, nyx, out);
    }
}